// Round 1
// baseline (277.939 us; speedup 1.0000x reference)
//
#include <hip/hip_runtime.h>
#include <hip/hip_bf16.h>
#include <math.h>

// Problem constants (from reference): B=8, N=100, D=768, H=768, TH=24, T=577.
#define PB   8
#define PN   100
#define PD   768
#define PT   577
#define PTH  24
#define BN_TOT (PB * PN)     // 800 pooled rows

// ---------------------------------------------------------------------------
// Kernel 1: ROI mean pooling.  One block per (b,n); 256 threads, 3 dims each.
// ---------------------------------------------------------------------------
__global__ __launch_bounds__(256) void pool_kernel(
    const float* __restrict__ patch,   // [B, 577, 768]
    const float* __restrict__ boxes,   // [B, N, 4]
    const int*   __restrict__ img_h,
    const int*   __restrict__ img_w,
    float* __restrict__ pooled)        // [B*N, 768]
{
    const int bn = blockIdx.x;               // 0..799
    const int b  = bn / PN;

    const float x1 = boxes[bn * 4 + 0];
    const float y1 = boxes[bn * 4 + 1];
    const float x2 = boxes[bn * 4 + 2];
    const float y2 = boxes[bn * 4 + 3];
    const float W  = (float)img_w[0];
    const float H  = (float)img_h[0];

    // to_patch(v, size) = floor(floor(v*size) / size * th)   (all f32, IEEE)
    auto to_patch = [](float v, float size) -> int {
        float pix = floorf(v * size);
        float t   = pix / size * (float)PTH;
        return (int)floorf(t);
    };

    int px1 = min(max(to_patch(x1, W), 0), PTH - 1);
    int py1 = min(max(to_patch(y1, H), 0), PTH - 1);
    int px2 = min(max(to_patch(x2, W), 1), PTH);
    int py2 = min(max(to_patch(y2, H), 1), PTH);
    if (px2 <= px1) px2 = px1 + 1;
    if (py2 <= py1) py2 = py1 + 1;

    const float cnt = (float)((px2 - px1) * (py2 - py1));

    const int t = threadIdx.x;
    float a0 = 0.f, a1 = 0.f, a2 = 0.f;
    for (int y = py1; y < py2; ++y) {
        for (int x = px1; x < px2; ++x) {
            const float* p = patch + (size_t)(b * PT + 1 + y * PTH + x) * PD;
            a0 += p[t];
            a1 += p[t + 256];
            a2 += p[t + 512];
        }
    }
    float* o = pooled + (size_t)bn * PD;
    o[t]       = a0 / cnt;
    o[t + 256] = a1 / cnt;
    o[t + 512] = a2 / cnt;
}

// ---------------------------------------------------------------------------
// Kernel 2: hab[m, 0:768]   = pooled[m,:] @ W1[0:768, :]   + b1   (= ha + b1)
//           hab[m, 768:1536]= pooled[m,:] @ W1[768:1536,:]        (= hb)
// Classic 64x64 tile, BK=16, 256 threads, 4x4 microtile. f32 vector ALU.
// ---------------------------------------------------------------------------
#define BM 64
#define BNT 64
#define BK 16

__global__ __launch_bounds__(256) void gemm_kernel(
    const float* __restrict__ A,    // pooled [800, 768]
    const float* __restrict__ W1,   // [1536, 768] row-major (row = input dim)
    const float* __restrict__ b1,   // [768]
    float* __restrict__ C)          // hab [800, 1536]
{
    __shared__ float As[BK][BM + 4];
    __shared__ float Bs[BK][BNT + 4];

    const int bm = blockIdx.y;           // 0..12
    const int bnb = blockIdx.x;          // 0..23
    const int m0 = bm * BM;
    const int n0 = bnb * BNT;
    // logical B[k][n]: n<768 -> W1[k*768+n]; n>=768 -> W1[(k+768)*768+(n-768)]
    const int rowoff = (n0 >= PD) ? PD : 0;
    const int col0   = n0 - rowoff;

    const int tid = threadIdx.x;
    const int tx = tid & 15;             // 0..15
    const int ty = tid >> 4;             // 0..15

    float acc[4][4] = {};

    for (int k0 = 0; k0 < PD; k0 += BK) {
#pragma unroll
        for (int l = 0; l < 4; ++l) {
            int e   = tid + l * 256;
            int row = e >> 4;            // 0..63
            int kk  = e & 15;
            int gm  = m0 + row;
            As[kk][row] = (gm < BN_TOT) ? A[(size_t)gm * PD + k0 + kk] : 0.0f;
        }
#pragma unroll
        for (int l = 0; l < 4; ++l) {
            int e   = tid + l * 256;
            int kk  = e >> 6;            // 0..15
            int col = e & 63;
            Bs[kk][col] = W1[(size_t)(k0 + kk + rowoff) * PD + col0 + col];
        }
        __syncthreads();

#pragma unroll
        for (int kk = 0; kk < BK; ++kk) {
            float ra[4], rb[4];
#pragma unroll
            for (int r = 0; r < 4; ++r) ra[r] = As[kk][ty * 4 + r];
#pragma unroll
            for (int c = 0; c < 4; ++c) rb[c] = Bs[kk][tx * 4 + c];
#pragma unroll
            for (int r = 0; r < 4; ++r)
#pragma unroll
                for (int c = 0; c < 4; ++c)
                    acc[r][c] = fmaf(ra[r], rb[c], acc[r][c]);
        }
        __syncthreads();
    }

#pragma unroll
    for (int r = 0; r < 4; ++r) {
        int gm = m0 + ty * 4 + r;
        if (gm >= BN_TOT) continue;
#pragma unroll
        for (int c = 0; c < 4; ++c) {
            int gn = n0 + tx * 4 + c;
            float v = acc[r][c];
            if (gn < PD) v += b1[gn];    // fold b1 into the ha half
            C[(size_t)gm * 1536 + gn] = v;
        }
    }
}

// ---------------------------------------------------------------------------
// Kernel 3: out[b,i,j] = sigmoid( sum_h relu(hab1[i,h] + hb[j,h]) * W2[h] + b2 )
// One block per (b,i); 4 waves x 25 j each; 12 elems/lane + shuffle reduce.
// ---------------------------------------------------------------------------
__global__ __launch_bounds__(256) void pair_kernel(
    const float* __restrict__ hab,   // [800, 1536]: [:,0:768]=ha+b1, [:,768:]=hb
    const float* __restrict__ W2,    // [768]
    const float* __restrict__ b2,    // [1]
    float* __restrict__ out)         // [B, N, N]
{
    __shared__ float sha[PD];
    __shared__ float sw2[PD];

    const int bn = blockIdx.x;       // (b,i)
    const int b  = bn / PN;
    const int t  = threadIdx.x;

    const float* ha = hab + (size_t)bn * 1536;
    sha[t]       = ha[t];
    sha[t + 256] = ha[t + 256];
    sha[t + 512] = ha[t + 512];
    sw2[t]       = W2[t];
    sw2[t + 256] = W2[t + 256];
    sw2[t + 512] = W2[t + 512];
    __syncthreads();

    const int wave = t >> 6;
    const int lane = t & 63;
    const float bb2 = b2[0];

    for (int j = wave; j < PN; j += 4) {
        const float* hb = hab + (size_t)(b * PN + j) * 1536 + PD;
        float acc = 0.f;
#pragma unroll
        for (int k = 0; k < 12; ++k) {
            int h = lane + 64 * k;
            float v = sha[h] + hb[h];
            acc = fmaf(fmaxf(v, 0.0f), sw2[h], acc);
        }
#pragma unroll
        for (int off = 32; off > 0; off >>= 1)
            acc += __shfl_down(acc, off, 64);
        if (lane == 0) {
            float logit = acc + bb2;
            out[(size_t)bn * PN + j] = 1.0f / (1.0f + expf(-logit));
        }
    }
}

// ---------------------------------------------------------------------------
extern "C" void kernel_launch(void* const* d_in, const int* in_sizes, int n_in,
                              void* d_out, int out_size, void* d_ws, size_t ws_size,
                              hipStream_t stream) {
    const float* patch = (const float*)d_in[0];   // [8,577,768]
    const float* boxes = (const float*)d_in[1];   // [8,100,4]
    const float* W1    = (const float*)d_in[2];   // [1536,768]
    const float* b1    = (const float*)d_in[3];   // [768]
    const float* W2    = (const float*)d_in[4];   // [768]
    const float* b2    = (const float*)d_in[5];   // [1]
    const int*   img_h = (const int*)d_in[6];
    const int*   img_w = (const int*)d_in[7];
    float* out = (float*)d_out;

    float* pooled = (float*)d_ws;                            // 800*768 f32
    float* hab    = pooled + (size_t)BN_TOT * PD;            // 800*1536 f32

    pool_kernel<<<BN_TOT, 256, 0, stream>>>(patch, boxes, img_h, img_w, pooled);

    dim3 ggrid(1536 / BNT, (BN_TOT + BM - 1) / BM);          // 24 x 13
    gemm_kernel<<<ggrid, 256, 0, stream>>>(pooled, W1, b1, hab);

    pair_kernel<<<BN_TOT, 256, 0, stream>>>(hab, W2, b2, out);
}

// Round 2
// 130.078 us; speedup vs baseline: 2.1367x; 2.1367x over previous
//
#include <hip/hip_runtime.h>
#include <hip/hip_bf16.h>
#include <math.h>

// Problem constants: B=8, N=100, D=768, H=768, TH=24, T=577.
#define PB   8
#define PN   100
#define PD   768
#define PT   577
#define PTH  24
#define BN_TOT (PB * PN)       // 800 pooled rows
#define MPAD   832             // 800 padded to 26*32

typedef __attribute__((ext_vector_type(8))) short bf16x8;   // 8 bf16 (4 VGPRs)
typedef __attribute__((ext_vector_type(4))) float f32x4;

// ---------------------------------------------------------------------------
// Kernel 1: x-prefix of the feature map into SAT rows 1..24 (col 0 zeroed).
// SAT layout: [B][25][25][768] f32.  SAT[b][Y][X][d] = sum_{y<Y,x<X} feat.
// One thread per (b, y, d): 8*24*768 = 147456 threads.
// ---------------------------------------------------------------------------
__global__ __launch_bounds__(256) void sat_x_kernel(
    const float* __restrict__ patch,   // [B,577,768]
    float* __restrict__ SAT)
{
    const int idx = blockIdx.x * 256 + threadIdx.x;    // 0..147455
    const int d = idx % PD;
    const int y = (idx / PD) % PTH;
    const int b = idx / (PD * PTH);

    const float* src = patch + ((size_t)(b * PT + 1 + y * PTH)) * PD + d;
    float* dst = SAT + ((size_t)((b * 25) + (y + 1)) * 25) * PD + d;

    dst[0] = 0.0f;                                     // col X=0
    float acc = 0.0f;
#pragma unroll
    for (int X = 1; X <= PTH; ++X) {
        acc += src[(size_t)(X - 1) * PD];
        dst[(size_t)X * PD] = acc;
    }
}

// ---------------------------------------------------------------------------
// Kernel 2: y-prefix of SAT in place (writes row Y=0 zeros).
// One thread per (b, X, d): 8*25*768 = 153600 threads.
// ---------------------------------------------------------------------------
__global__ __launch_bounds__(256) void sat_y_kernel(float* __restrict__ SAT)
{
    const int idx = blockIdx.x * 256 + threadIdx.x;    // 0..153599
    const int d = idx % PD;
    const int X = (idx / PD) % 25;
    const int b = idx / (PD * 25);

    float* col = SAT + ((size_t)(b * 25) * 25 + X) * PD + d;  // row stride 25*768
    col[0] = 0.0f;                                     // row Y=0
    float acc = 0.0f;
#pragma unroll
    for (int Y = 1; Y <= PTH; ++Y) {
        float* p = col + (size_t)Y * 25 * PD;
        acc += *p;
        *p = acc;
    }
}

// ---------------------------------------------------------------------------
// Kernel 3: W1 [1536,768] f32  ->  W1T [1536,768] bf16 where
//   W1T[n][k] = W1[k + 768*(n>=768)][n & 767]   (two 768x768 transposes)
// ---------------------------------------------------------------------------
__global__ __launch_bounds__(256) void cvt_w1t_kernel(
    const float* __restrict__ W1, __hip_bfloat16* __restrict__ W1T)
{
    __shared__ float tile[32][33];
    const int half = blockIdx.z;           // 0/1
    const int k0 = blockIdx.y * 32;        // row within half (input dim k)
    const int n0 = blockIdx.x * 32;        // col within half (hidden n)
    const int c = threadIdx.x & 31;
    const int r4 = threadIdx.x >> 5;       // 0..7

#pragma unroll
    for (int l = 0; l < 4; ++l) {
        int r = r4 + 8 * l;
        tile[r][c] = W1[(size_t)(half * PD + k0 + r) * PD + n0 + c];
    }
    __syncthreads();
#pragma unroll
    for (int l = 0; l < 4; ++l) {
        int r = r4 + 8 * l;                // n-offset within tile
        float v = tile[c][r];              // = W1[k0+c][n0+r]
        W1T[(size_t)(half * PD + n0 + r) * PD + k0 + c] = __float2bfloat16(v);
    }
}

// ---------------------------------------------------------------------------
// Kernel 4: pooled rows via 4 SAT lookups; emit bf16 [832][768], pad rows = 0.
// One block per row m; 256 threads x 3 d.
// ---------------------------------------------------------------------------
__global__ __launch_bounds__(256) void pool_sat_kernel(
    const float* __restrict__ SAT,
    const float* __restrict__ boxes,   // [800,4]
    const int*   __restrict__ img_h,
    const int*   __restrict__ img_w,
    __hip_bfloat16* __restrict__ pooledh)   // [832][768]
{
    const int m = blockIdx.x;          // 0..831
    const int t = threadIdx.x;
    __hip_bfloat16* o = pooledh + (size_t)m * PD;

    if (m >= BN_TOT) {
        o[t] = __float2bfloat16(0.0f);
        o[t + 256] = __float2bfloat16(0.0f);
        o[t + 512] = __float2bfloat16(0.0f);
        return;
    }

    const int b = m / PN;
    const float x1 = boxes[m * 4 + 0];
    const float y1 = boxes[m * 4 + 1];
    const float x2 = boxes[m * 4 + 2];
    const float y2 = boxes[m * 4 + 3];
    const float W  = (float)img_w[0];
    const float H  = (float)img_h[0];

    auto to_patch = [](float v, float size) -> int {
        float pix = floorf(v * size);
        float tt  = pix / size * (float)PTH;
        return (int)floorf(tt);
    };
    int px1 = min(max(to_patch(x1, W), 0), PTH - 1);
    int py1 = min(max(to_patch(y1, H), 0), PTH - 1);
    int px2 = min(max(to_patch(x2, W), 1), PTH);
    int py2 = min(max(to_patch(y2, H), 1), PTH);
    if (px2 <= px1) px2 = px1 + 1;
    if (py2 <= py1) py2 = py1 + 1;
    const float inv = 1.0f / (float)((px2 - px1) * (py2 - py1));

    const float* Sb = SAT + (size_t)b * 25 * 25 * PD;
    const float* S22 = Sb + ((size_t)py2 * 25 + px2) * PD;
    const float* S12 = Sb + ((size_t)py1 * 25 + px2) * PD;
    const float* S21 = Sb + ((size_t)py2 * 25 + px1) * PD;
    const float* S11 = Sb + ((size_t)py1 * 25 + px1) * PD;

#pragma unroll
    for (int l = 0; l < 3; ++l) {
        int d = t + l * 256;
        float s = (S22[d] - S12[d]) - (S21[d] - S11[d]);
        o[d] = __float2bfloat16(s * inv);
    }
}

// ---------------------------------------------------------------------------
// Kernel 5: bf16 MFMA GEMM.  C[832][1536] = A[832][768] * B^T,  B^T = W1T.
// Tile 32(M) x 64(N); 2 waves, each one 32x32 quadrant pair (2x2 frags).
// Fragments direct from global (all L2-resident).  b1 folded into n<768.
// ---------------------------------------------------------------------------
__global__ __launch_bounds__(128) void gemm_mfma_kernel(
    const __hip_bfloat16* __restrict__ A,    // pooled bf16 [832][768]
    const __hip_bfloat16* __restrict__ Bt,   // W1T bf16 [1536][768]
    const float* __restrict__ b1,            // [768]
    float* __restrict__ C)                   // hab [832][1536]
{
    const int bn = blockIdx.x;               // 0..23  (n tiles of 64)
    const int bm = blockIdx.y;               // 0..25  (m tiles of 32)
    const int wave = threadIdx.x >> 6;       // 0..1
    const int lane = threadIdx.x & 63;
    const int lm = lane & 15;
    const int g  = lane >> 4;                // 0..3  (k-group)

    const int m0 = bm * 32;
    const int n0 = bn * 64 + wave * 32;

    const __hip_bfloat16* pa0 = A  + (size_t)(m0 + lm) * PD + g * 8;
    const __hip_bfloat16* pa1 = pa0 + (size_t)16 * PD;
    const __hip_bfloat16* pb0 = Bt + (size_t)(n0 + lm) * PD + g * 8;
    const __hip_bfloat16* pb1 = pb0 + (size_t)16 * PD;

    f32x4 acc00 = {}, acc01 = {}, acc10 = {}, acc11 = {};

#pragma unroll 4
    for (int k0 = 0; k0 < PD; k0 += 32) {
        bf16x8 a0 = *(const bf16x8*)(pa0 + k0);
        bf16x8 a1 = *(const bf16x8*)(pa1 + k0);
        bf16x8 b0 = *(const bf16x8*)(pb0 + k0);
        bf16x8 b1v = *(const bf16x8*)(pb1 + k0);
        acc00 = __builtin_amdgcn_mfma_f32_16x16x32_bf16(a0, b0,  acc00, 0, 0, 0);
        acc01 = __builtin_amdgcn_mfma_f32_16x16x32_bf16(a0, b1v, acc01, 0, 0, 0);
        acc10 = __builtin_amdgcn_mfma_f32_16x16x32_bf16(a1, b0,  acc10, 0, 0, 0);
        acc11 = __builtin_amdgcn_mfma_f32_16x16x32_bf16(a1, b1v, acc11, 0, 0, 0);
    }

    // C/D layout (verified m89): col = lane&15, row = (lane>>4)*4 + reg
    const int rbase = g * 4;
#pragma unroll
    for (int r = 0; r < 4; ++r) {
        int row0 = m0 + rbase + r;
        int row1 = row0 + 16;
        int col0 = n0 + lm;
        int col1 = col0 + 16;
        float bb0 = (col0 < PD) ? b1[col0] : 0.0f;
        float bb1 = (col1 < PD) ? b1[col1] : 0.0f;
        C[(size_t)row0 * 1536 + col0] = acc00[r] + bb0;
        C[(size_t)row0 * 1536 + col1] = acc01[r] + bb1;
        C[(size_t)row1 * 1536 + col0] = acc10[r] + bb0;
        C[(size_t)row1 * 1536 + col1] = acc11[r] + bb1;
    }
}

// ---------------------------------------------------------------------------
// Kernel 6: out[b,i,j] = sigmoid( sum_h relu(ha'[i,h] + hb[j,h]) * W2[h] + b2 )
// ha' = ha + b1 (precomputed).  Block per (b,i); 4 waves x 25 j each.
// ha/W2 register-resident as float4; hb software-pipelined float4 loads.
// ---------------------------------------------------------------------------
__global__ __launch_bounds__(256) void pair_kernel(
    const float* __restrict__ hab,   // [832,1536]: [:,0:768]=ha+b1, [:,768:]=hb
    const float* __restrict__ W2,    // [768]
    const float* __restrict__ b2,    // [1]
    float* __restrict__ out)         // [B,N,N]
{
    const int bn = blockIdx.x;       // (b,i)
    const int b  = bn / PN;
    const int t  = threadIdx.x;
    const int wave = t >> 6;
    const int lane = t & 63;

    const float4* ha = (const float4*)(hab + (size_t)bn * 1536);
    const float4 sa0 = ha[lane], sa1 = ha[lane + 64], sa2 = ha[lane + 128];
    const float4* w2v = (const float4*)W2;
    const float4 w0 = w2v[lane], w1 = w2v[lane + 64], w2 = w2v[lane + 128];
    const float bb2 = b2[0];

    const float4* hbbase = (const float4*)(hab + (size_t)(b * PN) * 1536) + 192;

    int j = wave;
    const float4* hb = hbbase + (size_t)j * 384;
    float4 h0 = hb[lane], h1 = hb[lane + 64], h2 = hb[lane + 128];

    for (int s = 0; s < 25; ++s) {
        const float4 c0 = h0, c1 = h1, c2 = h2;
        const int jn = j + 4;
        if (s < 24) {
            const float4* hbn = hbbase + (size_t)jn * 384;
            h0 = hbn[lane]; h1 = hbn[lane + 64]; h2 = hbn[lane + 128];
        }
        float acc = 0.0f;
        acc = fmaf(fmaxf(sa0.x + c0.x, 0.0f), w0.x, acc);
        acc = fmaf(fmaxf(sa0.y + c0.y, 0.0f), w0.y, acc);
        acc = fmaf(fmaxf(sa0.z + c0.z, 0.0f), w0.z, acc);
        acc = fmaf(fmaxf(sa0.w + c0.w, 0.0f), w0.w, acc);
        acc = fmaf(fmaxf(sa1.x + c1.x, 0.0f), w1.x, acc);
        acc = fmaf(fmaxf(sa1.y + c1.y, 0.0f), w1.y, acc);
        acc = fmaf(fmaxf(sa1.z + c1.z, 0.0f), w1.z, acc);
        acc = fmaf(fmaxf(sa1.w + c1.w, 0.0f), w1.w, acc);
        acc = fmaf(fmaxf(sa2.x + c2.x, 0.0f), w2.x, acc);
        acc = fmaf(fmaxf(sa2.y + c2.y, 0.0f), w2.y, acc);
        acc = fmaf(fmaxf(sa2.z + c2.z, 0.0f), w2.z, acc);
        acc = fmaf(fmaxf(sa2.w + c2.w, 0.0f), w2.w, acc);
#pragma unroll
        for (int mask = 32; mask > 0; mask >>= 1)
            acc += __shfl_xor(acc, mask, 64);
        if (lane == 0)
            out[(size_t)bn * PN + j] = 1.0f / (1.0f + expf(-(acc + bb2)));
        j = jn;
    }
}

// ---------------------------------------------------------------------------
extern "C" void kernel_launch(void* const* d_in, const int* in_sizes, int n_in,
                              void* d_out, int out_size, void* d_ws, size_t ws_size,
                              hipStream_t stream) {
    const float* patch = (const float*)d_in[0];   // [8,577,768]
    const float* boxes = (const float*)d_in[1];   // [8,100,4]
    const float* W1    = (const float*)d_in[2];   // [1536,768]
    const float* b1    = (const float*)d_in[3];   // [768]
    const float* W2    = (const float*)d_in[4];   // [768]
    const float* b2    = (const float*)d_in[5];   // [1]
    const int*   img_h = (const int*)d_in[6];
    const int*   img_w = (const int*)d_in[7];
    float* out = (float*)d_out;

    // ws layout (bytes, 256-aligned):
    //   SAT      f32 [8][25][25][768]  = 15,360,000
    //   pooledh  bf16 [832][768]       =  1,277,952
    //   W1T      bf16 [1536][768]      =  2,359,296
    //   hab      f32 [832][1536]       =  5,111,808
    char* wsb = (char*)d_ws;
    float*          SAT     = (float*)(wsb);
    __hip_bfloat16* pooledh = (__hip_bfloat16*)(wsb + 15360000);
    __hip_bfloat16* W1T     = (__hip_bfloat16*)(wsb + 15360000 + 1277952);
    float*          hab     = (float*)(wsb + 15360000 + 1277952 + 2359296);

    sat_x_kernel<<<576, 256, 0, stream>>>(patch, SAT);
    cvt_w1t_kernel<<<dim3(24, 24, 2), 256, 0, stream>>>(W1, W1T);
    sat_y_kernel<<<600, 256, 0, stream>>>(SAT);
    pool_sat_kernel<<<MPAD, 256, 0, stream>>>(SAT, boxes, img_h, img_w, pooledh);
    gemm_mfma_kernel<<<dim3(24, 26), 128, 0, stream>>>(pooledh, W1T, b1, hab);
    pair_kernel<<<BN_TOT, 256, 0, stream>>>(hab, W2, b2, out);
}